// Round 1
// baseline (20060.516 us; speedup 1.0000x reference)
//
#include <hip/hip_runtime.h>
#include <hip/hip_bf16.h>

typedef __bf16 bf16x8 __attribute__((ext_vector_type(8)));
typedef float  f32x4  __attribute__((ext_vector_type(4)));

#define MFMA_BF16(a, b, c) __builtin_amdgcn_mfma_f32_16x16x32_bf16((a), (b), (c), 0, 0, 0)

constexpr int TT = 160, BB = 2048, HH = 512, EE = 64, VV = 128, G3 = 1536;
constexpr size_t LPROB_ELEMS = (size_t)TT * BB * VV;  // 41,943,040

__device__ __forceinline__ float fsigmoid(float x) {
  return 1.0f / (1.0f + __expf(-x));
}
__device__ __forceinline__ float ftanh(float x) {
  float ax = fabsf(x);
  float e = __expf(-2.0f * ax);
  float r = (1.0f - e) / (1.0f + e);
  return x < 0.0f ? -r : r;
}
// dual-dtype scalar load: isbf ? bf16[i] : f32[i]
__device__ __forceinline__ float ld(const void* p, long i, int isbf) {
  return isbf ? (float)((const __bf16*)p)[i] : ((const float*)p)[i];
}

// ---------------- dtype probe + barrier init ----------------
__global__ __launch_bounds__(256) void probe_dtype(
    const unsigned short* __restrict__ eh, int* __restrict__ flagp,
    unsigned* __restrict__ bar) {
  __shared__ int sb[256];
  int tid = threadIdx.x;
  // zero the 16 cluster barriers (16 x 64 words)
  for (int i = tid; i < 1024; i += 256) bar[i] = 0u;
  int cnt = 0;
  for (int i = tid; i < 4096; i += 256) {
    unsigned short u = eh[i];
    int e = (u >> 7) & 0xFF;
    if ((u & 0x7FFF) == 0 || (e >= 90 && e <= 150)) cnt++;
  }
  sb[tid] = cnt;
  __syncthreads();
  for (int s = 128; s > 0; s >>= 1) {
    if (tid < s) sb[tid] += sb[tid + s];
    __syncthreads();
  }
  if (tid == 0) *flagp = (sb[0] > 3072) ? 1 : 0;
}

// ---------------- prep kernels ----------------

__global__ __launch_bounds__(256) void conv_w(
    const void* __restrict__ Whh, const void* __restrict__ Wout,
    const void* __restrict__ bhh, const void* __restrict__ bout,
    const int* __restrict__ flagp,
    __bf16* __restrict__ Whh_b, __bf16* __restrict__ Wout_b,
    float* __restrict__ bhhn_f, float* __restrict__ bout_f) {
  const int isbf = *flagp;
  int idx = blockIdx.x * 256 + threadIdx.x;   // 3072 blocks -> 786,432 = 1536*512
  Whh_b[idx] = (__bf16)ld(Whh, idx, isbf);
  if (idx < VV * HH) Wout_b[idx] = (__bf16)ld(Wout, idx, isbf);
  if (idx < HH) bhhn_f[idx] = ld(bhh, 2 * HH + idx, isbf);
  if (idx < VV) bout_f[idx] = ld(bout, idx, isbf);
}

// gi_vocab[v][n] = relu(emb[v]) . W_ih[n] + b_ih[n] + (n < 1024 ? b_hh[n] : 0)
__global__ __launch_bounds__(256) void prep_gi(
    const void* __restrict__ emb, const void* __restrict__ Wih,
    const void* __restrict__ bih, const void* __restrict__ bhh,
    const int* __restrict__ flagp, float* __restrict__ gi) {
  const int isbf = *flagp;
  int idx = blockIdx.x * 256 + threadIdx.x;   // 768 blocks -> exactly 128*1536
  int v = idx / G3;
  int n = idx - v * G3;
  float s = 0.0f;
#pragma unroll 8
  for (int k = 0; k < EE; ++k) {
    float x = ld(emb, v * EE + k, isbf);
    x = x > 0.0f ? x : 0.0f;
    s += x * ld(Wih, (long)n * EE + k, isbf);
  }
  s += ld(bih, n, isbf);
  if (n < 2 * HH) s += ld(bhh, n, isbf);
  gi[idx] = s;
}

// h0 bf16 mirror (f32 state now lives in registers of the persistent kernel)
__global__ __launch_bounds__(256) void prep_hb0(
    const void* __restrict__ ehid, const int* __restrict__ flagp,
    __bf16* __restrict__ hb0) {
  const int isbf = *flagp;
  int idx = blockIdx.x * 256 + threadIdx.x;   // 4096 blocks -> 1,048,576
  hb0[idx] = (__bf16)ld(ehid, idx, isbf);
}

// ---------------- cluster barrier ----------------
// 16 independent clusters of 40 blocks (32 phase-1 + 8 phase-2). One counting
// barrier per cluster per step. Agent-scope release on arrival publishes this
// XCD's h-writes to LLC; agent-scope acquire on the generation spin
// invalidates stale L1/L2 lines before the next step's reads.
__device__ __forceinline__ void cbar(unsigned* __restrict__ bar, int cid,
                                     unsigned target) {
  __syncthreads();   // drains the block's stores (vmcnt 0 before s_barrier)
  if (threadIdx.x == 0) {
    unsigned* arr = bar + cid * 64;   // 256B-separated per cluster
    unsigned* gen = arr + 32;         // gen on its own 128B line
    unsigned old = __hip_atomic_fetch_add(arr, 1u, __ATOMIC_ACQ_REL,
                                          __HIP_MEMORY_SCOPE_AGENT);
    if (old == 39u) {
      __hip_atomic_store(arr, 0u, __ATOMIC_RELAXED, __HIP_MEMORY_SCOPE_AGENT);
      __hip_atomic_fetch_add(gen, 1u, __ATOMIC_RELEASE,
                             __HIP_MEMORY_SCOPE_AGENT);
    } else {
      while (__hip_atomic_load(gen, __ATOMIC_ACQUIRE,
                               __HIP_MEMORY_SCOPE_AGENT) < target)
        __builtin_amdgcn_s_sleep(1);
    }
  }
  __syncthreads();
}

// ---------------- persistent kernel ----------------
// Grid 640 x 256, ONE launch for all 161 steps. bid -> cluster cid = bid/40,
// sub = bid%40. sub<32: phase-1 (GRU recurrence, h f32 held in registers,
// colTile=sub, row-group grp=cid). sub>=32: phase-2 (logits + log_softmax of
// h(t-1), 16 rows each). Cluster-local barrier replaces the kernel boundary.
// __launch_bounds__(256,4): VGPR<=128 -> >=4 blocks/CU -> 1024 slots >= 640,
// so all blocks are co-resident and the barrier cannot deadlock.
__global__ __launch_bounds__(256, 4) void gru_persist(
    const __bf16* __restrict__ Whh, const __bf16* __restrict__ Wout,
    const float* __restrict__ bhhn_f, const float* __restrict__ bout_f,
    const float* __restrict__ gi, const int* __restrict__ tgt,
    const int* __restrict__ flagp, const void* __restrict__ ehid,
    __bf16* __restrict__ hb0, __bf16* __restrict__ hb1,
    void* __restrict__ outp, unsigned* __restrict__ bar) {
  __shared__ float llds[16 * 132];   // phase-2 only (8448 B)

  const int tid = threadIdx.x;
  const int bid = blockIdx.x;
  const int cid = bid / 40;
  const int sub = bid - cid * 40;
  const int w = tid >> 6;
  const int lane = tid & 63;
  const int q = lane >> 4;
  const int l16 = lane & 15;
  const int isbf = *flagp;
  const f32x4 fzero = {0.0f, 0.0f, 0.0f, 0.0f};

  if (sub < 32) {
    // ================= phase 1: GRU recurrence =================
    const int grp = cid;
    const int colTile = sub;
    const int mBase = grp * 128 + w * 32;
    const int c = colTile * 16 + l16;
    const float bhhn = bhhn_f[c];
    const size_t aOff = (size_t)(mBase + l16) * HH + q * 8;
    const __bf16* bRow = Whh + (size_t)c * HH + q * 8;

    // h f32 state: this thread owns rows mBase+ms*16+q*4+rg, column c
    float hreg[2][4];
#pragma unroll
    for (int ms = 0; ms < 2; ++ms)
#pragma unroll
      for (int rg = 0; rg < 4; ++rg) {
        int row = mBase + ms * 16 + q * 4 + rg;
        hreg[ms][rg] = ld(ehid, (long)row * HH + c, isbf);
      }

    for (int t = 0; t <= 160; ++t) {
      if (t < 160) {
        const __bf16* hbs = (t & 1) ? hb1 : hb0;   // h(t-1)
        __bf16* hbd = (t & 1) ? hb0 : hb1;         // h(t)

        f32x4 acc[2][3];
#pragma unroll
        for (int ms = 0; ms < 2; ++ms)
#pragma unroll
          for (int gg = 0; gg < 3; ++gg) acc[ms][gg] = fzero;

        const __bf16* aRow0 = hbs + aOff;
        const __bf16* aRow1 = aRow0 + 16 * HH;
#pragma unroll 4
        for (int k0 = 0; k0 < HH; k0 += 32) {
          bf16x8 a0 = *(const bf16x8*)(aRow0 + k0);
          bf16x8 a1 = *(const bf16x8*)(aRow1 + k0);
#pragma unroll
          for (int gg = 0; gg < 3; ++gg) {
            bf16x8 bf = *(const bf16x8*)(bRow + (size_t)gg * (HH * HH) + k0);
            acc[0][gg] = MFMA_BF16(a0, bf, acc[0][gg]);
            acc[1][gg] = MFMA_BF16(a1, bf, acc[1][gg]);
          }
        }

#pragma unroll
        for (int ms = 0; ms < 2; ++ms) {
#pragma unroll
          for (int rg = 0; rg < 4; ++rg) {
            int row = mBase + ms * 16 + q * 4 + rg;
            int tk = (t == 0) ? 0 : tgt[row * TT + (t - 1)];
            const float* gv = gi + (size_t)tk * G3 + c;
            float r_ = fsigmoid(acc[ms][0][rg] + gv[0]);
            float z_ = fsigmoid(acc[ms][1][rg] + gv[HH]);
            float n_ = ftanh(gv[2 * HH] + r_ * (acc[ms][2][rg] + bhhn));
            float hv = (1.0f - z_) * n_ + z_ * hreg[ms][rg];
            hreg[ms][rg] = hv;
            hbd[(size_t)row * HH + c] = (__bf16)hv;
          }
        }
      } else {
        // t == 160: write final hidden straight from registers
        if (isbf) {
          __bf16* dst = (__bf16*)outp + LPROB_ELEMS;
#pragma unroll
          for (int ms = 0; ms < 2; ++ms)
#pragma unroll
            for (int rg = 0; rg < 4; ++rg) {
              int row = mBase + ms * 16 + q * 4 + rg;
              dst[(size_t)row * HH + c] = (__bf16)hreg[ms][rg];
            }
        } else {
          float* dst = (float*)outp + LPROB_ELEMS;
#pragma unroll
          for (int ms = 0; ms < 2; ++ms)
#pragma unroll
            for (int rg = 0; rg < 4; ++rg) {
              int row = mBase + ms * 16 + q * 4 + rg;
              dst[(size_t)row * HH + c] = hreg[ms][rg];
            }
        }
      }
      if (t < 160) cbar(bar, cid, (unsigned)(t + 1));
    }
  } else {
    // ================= phase 2: logits + log_softmax =================
    const int rb = cid * 128 + (sub - 32) * 16;
    const size_t aOffBase = (size_t)(rb + l16) * HH + q * 8;
    const __bf16* bR0 = Wout + (size_t)(w * 32 + l16) * HH + q * 8;
    const __bf16* bR1 = bR0 + 16 * HH;
    const float bo0 = bout_f[(w * 2 + 0) * 16 + l16];
    const float bo1 = bout_f[(w * 2 + 1) * 16 + l16];

    for (int t = 0; t <= 160; ++t) {
      if (t >= 1) {
        const __bf16* hbs = (t & 1) ? hb1 : hb0;   // h(t-1)
        const __bf16* aR = hbs + aOffBase;
        f32x4 acc2[2];
        acc2[0] = fzero; acc2[1] = fzero;
#pragma unroll 4
        for (int k0 = 0; k0 < HH; k0 += 32) {
          bf16x8 a  = *(const bf16x8*)(aR + k0);
          bf16x8 b0 = *(const bf16x8*)(bR0 + k0);
          bf16x8 b1 = *(const bf16x8*)(bR1 + k0);
          acc2[0] = MFMA_BF16(a, b0, acc2[0]);
          acc2[1] = MFMA_BF16(a, b1, acc2[1]);
        }
#pragma unroll
        for (int j = 0; j < 2; ++j) {
          int col = (w * 2 + j) * 16 + l16;
          float bo = j ? bo1 : bo0;
#pragma unroll
          for (int rg = 0; rg < 4; ++rg)
            llds[(q * 4 + rg) * 132 + col] = acc2[j][rg] + bo;
        }
        __syncthreads();
        {
          int row = tid >> 4, seg = tid & 15;
          const float* lr = &llds[row * 132 + seg * 8];
          float x[8];
          float m = -3.0e38f;
#pragma unroll
          for (int i = 0; i < 8; ++i) { x[i] = lr[i]; m = fmaxf(m, x[i]); }
#pragma unroll
          for (int d = 1; d < 16; d <<= 1) m = fmaxf(m, __shfl_xor(m, d, 16));
          float s = 0.0f;
#pragma unroll
          for (int i = 0; i < 8; ++i) s += __expf(x[i] - m);
#pragma unroll
          for (int d = 1; d < 16; d <<= 1) s += __shfl_xor(s, d, 16);
          float lg = m + __logf(s);
          size_t ofs = (size_t)(t - 1) * (BB * VV) + (size_t)(rb + row) * VV + seg * 8;
          if (isbf) {
            bf16x8 ov;
#pragma unroll
            for (int i = 0; i < 8; ++i) ov[i] = (__bf16)(x[i] - lg);
            *(bf16x8*)((__bf16*)outp + ofs) = ov;
          } else {
            f32x4 o0, o1;
#pragma unroll
            for (int i = 0; i < 4; ++i) { o0[i] = x[i] - lg; o1[i] = x[4 + i] - lg; }
            float* dst = (float*)outp + ofs;
            *(f32x4*)dst = o0;
            *(f32x4*)(dst + 4) = o1;
          }
        }
      }
      if (t < 160) cbar(bar, cid, (unsigned)(t + 1));
    }
  }
}

// ---------------- launcher ----------------
extern "C" void kernel_launch(void* const* d_in, const int* in_sizes, int n_in,
                              void* d_out, int out_size, void* d_ws, size_t ws_size,
                              hipStream_t stream) {
  // setup_inputs order:
  // 0 encoder_outputs (unused), 1 encoder_hidden, 2 target_tensor, 3 embedding,
  // 4 W_ih, 5 W_hh, 6 b_ih, 7 b_hh, 8 W_out, 9 b_out
  const void* ehid = d_in[1];
  const int*  tgt  = (const int*)d_in[2];
  const void* emb  = d_in[3];
  const void* Wih  = d_in[4];
  const void* Whh  = d_in[5];
  const void* bih  = d_in[6];
  const void* bhh  = d_in[7];
  const void* Wout = d_in[8];
  const void* bout = d_in[9];

  // workspace carve (~6.4 MiB), all offsets 256B-aligned
  char* ws = (char*)d_ws;
  int*      flagp  = (int*)(ws + 0);              //     256 B
  unsigned* bar    = (unsigned*)(ws + 256);       //   4,096 B: 16 clusters x 64 words
  float*    gi     = (float*)(ws + 4608);         // 786,432 B: [128][1536] f32
  __bf16*   hb0    = (__bf16*)(ws + 791040);      // 2,097,152 B: h bf16 ping
  __bf16*   hb1    = (__bf16*)(ws + 2888192);     // 2,097,152 B: h bf16 pong
  __bf16*   Whh_b  = (__bf16*)(ws + 4985344);     // 1,572,864 B
  __bf16*   Wout_b = (__bf16*)(ws + 6558208);     //   131,072 B
  float*    bhhn_f = (float*)(ws + 6689280);      //     2,048 B
  float*    bout_f = (float*)(ws + 6691328);      //       512 B

  probe_dtype<<<1, 256, 0, stream>>>((const unsigned short*)ehid, flagp, bar);
  conv_w<<<3072, 256, 0, stream>>>(Whh, Wout, bhh, bout, flagp,
                                   Whh_b, Wout_b, bhhn_f, bout_f);
  prep_gi<<<768, 256, 0, stream>>>(emb, Wih, bih, bhh, flagp, gi);
  prep_hb0<<<4096, 256, 0, stream>>>(ehid, flagp, hb0);

  gru_persist<<<640, 256, 0, stream>>>(Whh_b, Wout_b, bhhn_f, bout_f, gi, tgt,
                                       flagp, ehid, hb0, hb1, d_out, bar);
}

// Round 3
// 9965.752 us; speedup vs baseline: 2.0129x; 2.0129x over previous
//
#include <hip/hip_runtime.h>
#include <hip/hip_bf16.h>

typedef __bf16 bf16x8 __attribute__((ext_vector_type(8)));
typedef float  f32x4  __attribute__((ext_vector_type(4)));

#define MFMA_BF16(a, b, c) __builtin_amdgcn_mfma_f32_16x16x32_bf16((a), (b), (c), 0, 0, 0)

constexpr int TT = 160, BB = 2048, HH = 512, EE = 64, VV = 128, G3 = 1536;
constexpr size_t LPROB_ELEMS = (size_t)TT * BB * VV;  // 41,943,040
constexpr int RB = 32;                // rows (batch) per block
constexpr int NBLK = BB / RB;         // 64 blocks
constexpr int HCH = 528;              // LDS h chunk stride (bytes): 32 rows*16B + 16B pad

__device__ __forceinline__ float fsigmoid(float x) {
  return 1.0f / (1.0f + __expf(-x));
}
__device__ __forceinline__ float ftanh(float x) {
  float ax = fabsf(x);
  float e = __expf(-2.0f * ax);
  float r = (1.0f - e) / (1.0f + e);
  return x < 0.0f ? -r : r;
}
// dual-dtype scalar load: isbf ? bf16[i] : f32[i]
__device__ __forceinline__ float ld(const void* p, long i, int isbf) {
  return isbf ? (float)((const __bf16*)p)[i] : ((const float*)p)[i];
}

// h LDS layout: k-chunked [64 chunks][32 rows][8 cols] bf16, chunk stride 528B.
// A-frag read (16 lanes, rows 0..15, one 16B chunk) -> stride-16B = conflict-free.
__device__ __forceinline__ int hoff(int row, int ce) {
  return (ce >> 3) * HCH + row * 16 + ((ce & 7) << 1);
}

// ---------------- dtype probe ----------------
__global__ __launch_bounds__(256) void probe_dtype(
    const unsigned short* __restrict__ eh, int* __restrict__ flagp) {
  __shared__ int sb[256];
  int tid = threadIdx.x;
  int cnt = 0;
  for (int i = tid; i < 4096; i += 256) {
    unsigned short u = eh[i];
    int e = (u >> 7) & 0xFF;
    if ((u & 0x7FFF) == 0 || (e >= 90 && e <= 150)) cnt++;
  }
  sb[tid] = cnt;
  __syncthreads();
  for (int s = 128; s > 0; s >>= 1) {
    if (tid < s) sb[tid] += sb[tid + s];
    __syncthreads();
  }
  if (tid == 0) *flagp = (sb[0] > 3072) ? 1 : 0;
}

// ---------------- prep kernels ----------------
__global__ __launch_bounds__(256) void conv_w(
    const void* __restrict__ Whh, const void* __restrict__ Wout,
    const void* __restrict__ bhh, const void* __restrict__ bout,
    const int* __restrict__ flagp,
    __bf16* __restrict__ Whh_b, __bf16* __restrict__ Wout_b,
    float* __restrict__ bhhn_f, float* __restrict__ bout_f) {
  const int isbf = *flagp;
  int idx = blockIdx.x * 256 + threadIdx.x;   // 3072 blocks -> 786,432 = 1536*512
  Whh_b[idx] = (__bf16)ld(Whh, idx, isbf);
  if (idx < VV * HH) Wout_b[idx] = (__bf16)ld(Wout, idx, isbf);
  if (idx < HH) bhhn_f[idx] = ld(bhh, 2 * HH + idx, isbf);
  if (idx < VV) bout_f[idx] = ld(bout, idx, isbf);
}

// gi[v][c][g] = relu(emb[v]) . W_ih[g*512+c] + b_ih[g*512+c] + (g<2 ? b_hh[g*512+c] : 0)
// Interleaved [vocab][512][3] layout: the 3 gate values for one (token,col)
// are 12 contiguous bytes -> single-cache-line epilogue reads.
__global__ __launch_bounds__(256) void prep_gi(
    const void* __restrict__ emb, const void* __restrict__ Wih,
    const void* __restrict__ bih, const void* __restrict__ bhh,
    const int* __restrict__ flagp, float* __restrict__ gi) {
  const int isbf = *flagp;
  int idx = blockIdx.x * 256 + threadIdx.x;   // 768 blocks -> exactly 128*1536
  int v = idx / G3;
  int n = idx - v * G3;
  float s = 0.0f;
#pragma unroll 8
  for (int k = 0; k < EE; ++k) {
    float x = ld(emb, v * EE + k, isbf);
    x = x > 0.0f ? x : 0.0f;
    s += x * ld(Wih, (long)n * EE + k, isbf);
  }
  s += ld(bih, n, isbf);
  if (n < 2 * HH) s += ld(bhh, n, isbf);
  int g = n >> 9;        // gate 0..2 (r,z,n)
  int c = n & 511;       // col 0..511
  gi[((size_t)v * HH + c) * 3 + g] = s;
}

// ---------------- fused persistent kernel (no inter-block sync) ----------------
// 64 blocks x 1024 threads. Block bid owns batch rows [bid*32, bid*32+32) and
// runs the ENTIRE 160-step recurrence + logits + log_softmax for those rows.
// h(t): bf16 in LDS (MFMA A operand) + f32 in REGISTERS (hreg, thread-private).
// Weights (Whh 1.5MB + Wout 128KB bf16) stream from L2 each step.
// 16 waves: wave w owns h-cols [w*32, w*32+32) for all 3 gates (GRU), and
// logits tile (m=w>>3, vocab-tile=w&7). Only __syncthreads() — no atomics.
__global__ __launch_bounds__(1024, 2) void gru_fused(
    const __bf16* __restrict__ Whh, const __bf16* __restrict__ Wout,
    const float* __restrict__ bhhn_f, const float* __restrict__ bout_f,
    const float* __restrict__ gi, const int* __restrict__ tgt,
    const int* __restrict__ flagp, const void* __restrict__ ehid,
    void* __restrict__ outp) {
  __shared__ __align__(16) char hlds[64 * HCH];   // 33,792 B  h bf16, k-chunked
  __shared__ float llds[RB * 132];                // 16,896 B  logits staging

  const int tid = threadIdx.x;
  const int bid = blockIdx.x;
  const int rBase = bid * RB;
  const int w = tid >> 6;          // wave 0..15
  const int lane = tid & 63;
  const int q = lane >> 4;
  const int l16 = lane & 15;
  const int isbf = *flagp;
  const f32x4 fzero = {0.0f, 0.0f, 0.0f, 0.0f};

  // ---- prologue: h0 -> LDS (bf16, cooperative) + registers (f32, owned) ----
  for (int i = tid; i < RB * HH; i += 1024) {
    int row = i >> 9, ce = i & 511;
    float v = ld(ehid, (long)(rBase + row) * HH + ce, isbf);
    *(__bf16*)(hlds + hoff(row, ce)) = (__bf16)v;
  }

  // thread-owned f32 state: rows m*16+q*4+rg, cols w*32+ct*16+l16
  float hreg[2][2][4];   // [ct][m][rg]
#pragma unroll
  for (int ct = 0; ct < 2; ++ct)
#pragma unroll
    for (int m = 0; m < 2; ++m)
#pragma unroll
      for (int rg = 0; rg < 4; ++rg) {
        int row = m * 16 + q * 4 + rg;
        int c = w * 32 + ct * 16 + l16;
        hreg[ct][m][rg] = ld(ehid, (long)(rBase + row) * HH + c, isbf);
      }
  __syncthreads();

  // hoisted B pointers: 3 gates x 2 col-subtiles, n = g*512 + w*32 + ct*16 + l16
  const __bf16* bp[3][2];
#pragma unroll
  for (int g = 0; g < 3; ++g)
#pragma unroll
    for (int ct = 0; ct < 2; ++ct)
      bp[g][ct] = Whh + (size_t)(g * HH + w * 32 + ct * 16 + l16) * HH + q * 8;

  const float bh[2] = {bhhn_f[w * 32 + l16], bhhn_f[w * 32 + 16 + l16]};

  const int mw = w >> 3;           // logits m-tile 0..1
  const int nt = w & 7;            // logits vocab-tile 0..7
  const __bf16* bpo = Wout + (size_t)(nt * 16 + l16) * HH + q * 8;
  const float boL = bout_f[nt * 16 + l16];

  for (int s = 0; s < TT; ++s) {
    // ---- gh = h(t-1) @ Whh^T  for 32 rows x (3 gates x 32 cols) ----
    f32x4 acc[2][3][2];   // [m][gate][ct]
#pragma unroll
    for (int m = 0; m < 2; ++m)
#pragma unroll
      for (int g = 0; g < 3; ++g)
#pragma unroll
        for (int ct = 0; ct < 2; ++ct) acc[m][g][ct] = fzero;

#pragma unroll 4
    for (int k0 = 0; k0 < HH; k0 += 32) {
      const int kb = ((k0 >> 3) + q) * HCH + l16 * 16;
      bf16x8 a0 = *(const bf16x8*)(hlds + kb);
      bf16x8 a1 = *(const bf16x8*)(hlds + kb + 256);
#pragma unroll
      for (int g = 0; g < 3; ++g)
#pragma unroll
        for (int ct = 0; ct < 2; ++ct) {
          bf16x8 b = *(const bf16x8*)(bp[g][ct] + k0);
          acc[0][g][ct] = MFMA_BF16(a0, b, acc[0][g][ct]);
          acc[1][g][ct] = MFMA_BF16(a1, b, acc[1][g][ct]);
        }
    }

    // ---- GRU epilogue: own (row, c) elements; f32 state in regs; pack bf16 ----
    bf16x8 hn[2];   // 16 new h values as bf16, [ct][m*4+rg]
#pragma unroll
    for (int m = 0; m < 2; ++m)
#pragma unroll
      for (int rg = 0; rg < 4; ++rg) {
        const int row = m * 16 + q * 4 + rg;
        const int tk = (s == 0) ? 0 : tgt[(long)(rBase + row) * TT + (s - 1)];
        const float* gbase = gi + (size_t)tk * (HH * 3);
#pragma unroll
        for (int ct = 0; ct < 2; ++ct) {
          const int c = w * 32 + ct * 16 + l16;
          const float* gv = gbase + c * 3;    // [r, z, n] contiguous
          float r_ = fsigmoid(acc[m][0][ct][rg] + gv[0]);
          float z_ = fsigmoid(acc[m][1][ct][rg] + gv[1]);
          float n_ = ftanh(gv[2] + r_ * (acc[m][2][ct][rg] + bh[ct]));
          float hv = (1.0f - z_) * n_ + z_ * hreg[ct][m][rg];
          hreg[ct][m][rg] = hv;
          hn[ct][m * 4 + rg] = (__bf16)hv;
        }
      }
    __syncthreads();   // all waves finished reading h(t-1) from LDS

#pragma unroll
    for (int ct = 0; ct < 2; ++ct) {
      const int c = w * 32 + ct * 16 + l16;
#pragma unroll
      for (int m = 0; m < 2; ++m)
#pragma unroll
        for (int rg = 0; rg < 4; ++rg)
          *(__bf16*)(hlds + hoff(m * 16 + q * 4 + rg, c)) = hn[ct][m * 4 + rg];
    }
    __syncthreads();   // h(t) LDS ready

    // ---- logits = h(t) @ Wout^T : per wave one 16x16 tile ----
    f32x4 acc2 = fzero;
#pragma unroll 4
    for (int k0 = 0; k0 < HH; k0 += 32) {
      bf16x8 a = *(const bf16x8*)(hlds + ((k0 >> 3) + q) * HCH + (mw * 16 + l16) * 16);
      bf16x8 b = *(const bf16x8*)(bpo + k0);
      acc2 = MFMA_BF16(a, b, acc2);
    }
    {
      const int col = nt * 16 + l16;
#pragma unroll
      for (int rg = 0; rg < 4; ++rg)
        llds[(mw * 16 + q * 4 + rg) * 132 + col] = acc2[rg] + boL;
    }
    __syncthreads();   // logits staged

    // ---- log_softmax: 32 rows x 16 threads (8 cols each) ----
    if (tid < RB * 16) {
      int row = tid >> 4, seg = tid & 15;
      const float* lr = &llds[row * 132 + seg * 8];
      float x[8];
      float m = -3.0e38f;
#pragma unroll
      for (int i = 0; i < 8; ++i) { x[i] = lr[i]; m = fmaxf(m, x[i]); }
#pragma unroll
      for (int d = 1; d < 16; d <<= 1) m = fmaxf(m, __shfl_xor(m, d, 16));
      float ssum = 0.0f;
#pragma unroll
      for (int i = 0; i < 8; ++i) ssum += __expf(x[i] - m);
#pragma unroll
      for (int d = 1; d < 16; d <<= 1) ssum += __shfl_xor(ssum, d, 16);
      float lg = m + __logf(ssum);
      size_t ofs = (size_t)s * (BB * VV) + (size_t)(rBase + row) * VV + seg * 8;
      if (isbf) {
        bf16x8 ov;
#pragma unroll
        for (int i = 0; i < 8; ++i) ov[i] = (__bf16)(x[i] - lg);
        *(bf16x8*)((__bf16*)outp + ofs) = ov;
      } else {
        f32x4 o0, o1;
#pragma unroll
        for (int i = 0; i < 4; ++i) { o0[i] = x[i] - lg; o1[i] = x[4 + i] - lg; }
        float* dst = (float*)outp + ofs;
        *(f32x4*)dst = o0;
        *(f32x4*)(dst + 4) = o1;
      }
    }
    // no barrier needed here: next write to llds is 2 barriers away; softmax
    // readers must pass those barriers before any wave can overwrite llds.
  }

  // ---- final hidden h(160): exact f32 from registers -> output ----
#pragma unroll
  for (int ct = 0; ct < 2; ++ct) {
    const int c = w * 32 + ct * 16 + l16;
#pragma unroll
    for (int m = 0; m < 2; ++m)
#pragma unroll
      for (int rg = 0; rg < 4; ++rg) {
        const int row = m * 16 + q * 4 + rg;
        size_t o = LPROB_ELEMS + (size_t)(rBase + row) * HH + c;
        if (isbf) ((__bf16*)outp)[o] = (__bf16)hreg[ct][m][rg];
        else      ((float*)outp)[o] = hreg[ct][m][rg];
      }
  }
}

// ---------------- launcher ----------------
extern "C" void kernel_launch(void* const* d_in, const int* in_sizes, int n_in,
                              void* d_out, int out_size, void* d_ws, size_t ws_size,
                              hipStream_t stream) {
  // setup_inputs order:
  // 0 encoder_outputs (unused), 1 encoder_hidden, 2 target_tensor, 3 embedding,
  // 4 W_ih, 5 W_hh, 6 b_ih, 7 b_hh, 8 W_out, 9 b_out
  const void* ehid = d_in[1];
  const int*  tgt  = (const int*)d_in[2];
  const void* emb  = d_in[3];
  const void* Wih  = d_in[4];
  const void* Whh  = d_in[5];
  const void* bih  = d_in[6];
  const void* bhh  = d_in[7];
  const void* Wout = d_in[8];
  const void* bout = d_in[9];

  // workspace carve (~2.5 MiB), all offsets 256B-aligned
  char* ws = (char*)d_ws;
  int*    flagp  = (int*)(ws + 0);              //       256 B
  float*  gi     = (float*)(ws + 256);          //   786,432 B: [128][512][3] f32
  __bf16* Whh_b  = (__bf16*)(ws + 786688);      // 1,572,864 B
  __bf16* Wout_b = (__bf16*)(ws + 2359552);     //   131,072 B
  float*  bhhn_f = (float*)(ws + 2490624);      //     2,048 B
  float*  bout_f = (float*)(ws + 2492672);      //       512 B

  probe_dtype<<<1, 256, 0, stream>>>((const unsigned short*)ehid, flagp);
  conv_w<<<3072, 256, 0, stream>>>(Whh, Wout, bhh, bout, flagp,
                                   Whh_b, Wout_b, bhhn_f, bout_f);
  prep_gi<<<768, 256, 0, stream>>>(emb, Wih, bih, bhh, flagp, gi);

  gru_fused<<<NBLK, 1024, 0, stream>>>(Whh_b, Wout_b, bhhn_f, bout_f, gi, tgt,
                                       flagp, ehid, d_out);
}